// Round 10
// baseline (61.209 us; speedup 1.0000x reference)
//
#include <hip/hip_runtime.h>
#include <hip/hip_bf16.h>

typedef __attribute__((ext_vector_type(8))) short bf16x8;
typedef __attribute__((ext_vector_type(4))) float f32x4;

#define NGRAPH   4096
#define NNODES   262144
#define LATENT   256
#define H2       512
#define HID      256
#define NF       128

#define PREP_BLOCKS 1152       // weight transpose (294912 / 256)
#define SCAN_BLOCKS 64         // seg -> offs scan
#define IPT         16         // ints per scan thread

#define GPB      8             // graphs per block (merged kernel)
#define MTHREADS 512           // 8 waves; wave = graph for scatter
#define MBLOCKS  (NGRAPH / GPB)            // 512 -> 2 blocks/CU

// padded LDS strides
#define ZS_S 264
#define HS_S 520
#define HD_S 264

static __device__ __forceinline__ short f2bf(float x) {
    union { float f; unsigned u; } c; c.f = x;
    unsigned r = c.u + 0x7fffu + ((c.u >> 16) & 1u);   // RTNE
    return (short)(r >> 16);
}

// ---------------------------------------------------------------------------
// prep: weight transpose -> bf16 (blocks 0..1151)  +  seg scan -> offs
// (blocks 1152..1215).  offs[g] = first node index with seg >= g.
// ---------------------------------------------------------------------------
__global__ __launch_bounds__(256) void prep_kernel(
    const float* __restrict__ wlp, const float* __restrict__ w1,
    const float* __restrict__ w2, const int* __restrict__ seg,
    short* __restrict__ wlp_t, short* __restrict__ w1_t, short* __restrict__ w2_t,
    int* __restrict__ offs)
{
    const int b = blockIdx.x;
    if (b < PREP_BLOCKS) {
        int i = b * 256 + threadIdx.x;
        if (i < LATENT * H2) {                       // wlp_t [512][256]
            int n = i >> 8, k = i & 255;
            wlp_t[i] = f2bf(wlp[k * H2 + n]);
        } else if (i < 2 * LATENT * H2) {            // w1_t [256][512]
            int j = i - LATENT * H2;
            int n = j >> 9, k = j & 511;
            w1_t[j] = f2bf(w1[k * HID + n]);
        } else if (i < 2 * LATENT * H2 + HID * NF) { // w2_t [128][256]
            int j = i - 2 * LATENT * H2;
            int n = j >> 8, k = j & 255;
            w2_t[j] = f2bf(w2[k * NF + n]);
        }
    } else {
        // scan: thread handles IPT consecutive node indices
        const int st = (b - PREP_BLOCKS) * 256 + threadIdx.x;   // 0..16383
        const int base = st * IPT;
        int prev = (base == 0) ? -1 : seg[base - 1];
        int cur[IPT];
        #pragma unroll
        for (int j = 0; j < IPT; ++j) cur[j] = seg[base + j];
        #pragma unroll
        for (int j = 0; j < IPT; ++j) {
            int i = base + j;
            int s = cur[j];
            if (s != prev) {
                for (int g = prev + 1; g <= s; ++g) offs[g] = i;
            }
            prev = s;
        }
        if (base + IPT == NNODES) {                  // tail: (seg[N-1], NGRAPH]
            for (int g = prev + 1; g <= NGRAPH; ++g) offs[g] = NNODES;
        }
    }
}

// ---------------------------------------------------------------------------
// merged kernel: per-block 8-graph MLP (MFMA, rows 8-15 of each 16-row tile
// are garbage and never stored) + per-wave streaming broadcast of the block's
// own graphs via LDS.  512 blocks -> 2/CU: block A's store phase overlaps
// block B's compute phase.
// ---------------------------------------------------------------------------
__global__ __launch_bounds__(MTHREADS, 4) void mlp_scatter_kernel(
    const float* __restrict__ z, const int* __restrict__ offs,
    const short* __restrict__ wlp_t, const short* __restrict__ w1_t,
    const short* __restrict__ w2_t,
    const float* __restrict__ b_lp, const float* __restrict__ b1,
    const float* __restrict__ b2,
    float* __restrict__ out)
{
    __shared__ short zs[16 * ZS_S];
    __shared__ short hs[16 * HS_S];
    __shared__ short hd[16 * HD_S];
    __shared__ float ous[16 * NF];

    const int tid = threadIdx.x;
    const int w   = tid >> 6;          // wave 0..7
    const int l15 = tid & 15;
    const int lq  = (tid >> 4) & 3;
    const int gbase = blockIdx.x * GPB;

    // ---- stage z: 8x256 fp32 -> bf16 LDS rows 0-7 (512 float4 = 1/thread)
    {
        const float4* zsrc = (const float4*)(z + (size_t)gbase * LATENT);
        int row = tid >> 6, c4 = tid & 63;
        float4 v = zsrc[tid];
        short4 s4;
        s4.x = f2bf(v.x); s4.y = f2bf(v.y); s4.z = f2bf(v.z); s4.w = f2bf(v.w);
        *(short4*)&zs[row * ZS_S + c4 * 4] = s4;
    }
    __syncthreads();

    // ---- h = relu(z @ Wlp + b_lp), [16(8 valid) x 512], K=256
    {
        const int cb = w * 64;
        f32x4 acc[4];
        #pragma unroll
        for (int ct = 0; ct < 4; ++ct) acc[ct] = (f32x4){0.f, 0.f, 0.f, 0.f};
        #pragma unroll
        for (int ks = 0; ks < LATENT / 32; ++ks) {
            bf16x8 a = *(const bf16x8*)&zs[l15 * ZS_S + ks * 32 + lq * 8];
            #pragma unroll
            for (int ct = 0; ct < 4; ++ct) {
                bf16x8 b = *(const bf16x8*)&wlp_t[(cb + ct * 16 + l15) * LATENT + ks * 32 + lq * 8];
                acc[ct] = __builtin_amdgcn_mfma_f32_16x16x32_bf16(a, b, acc[ct], 0, 0, 0);
            }
        }
        #pragma unroll
        for (int ct = 0; ct < 4; ++ct) {
            const int col = cb + ct * 16 + l15;
            const float bias = b_lp[col];
            #pragma unroll
            for (int i = 0; i < 4; ++i) {
                float v = acc[ct][i] + bias;
                hs[(lq * 4 + i) * HS_S + col] = f2bf(fmaxf(v, 0.f));
            }
        }
    }
    __syncthreads();

    // ---- hid = relu(h @ W1 + b1), [16(8) x 256], K=512
    {
        const int cb = w * 32;
        f32x4 acc[2];
        #pragma unroll
        for (int ct = 0; ct < 2; ++ct) acc[ct] = (f32x4){0.f, 0.f, 0.f, 0.f};
        #pragma unroll
        for (int ks = 0; ks < H2 / 32; ++ks) {
            bf16x8 a = *(const bf16x8*)&hs[l15 * HS_S + ks * 32 + lq * 8];
            #pragma unroll
            for (int ct = 0; ct < 2; ++ct) {
                bf16x8 b = *(const bf16x8*)&w1_t[(cb + ct * 16 + l15) * H2 + ks * 32 + lq * 8];
                acc[ct] = __builtin_amdgcn_mfma_f32_16x16x32_bf16(a, b, acc[ct], 0, 0, 0);
            }
        }
        #pragma unroll
        for (int ct = 0; ct < 2; ++ct) {
            const int col = cb + ct * 16 + l15;
            const float bias = b1[col];
            #pragma unroll
            for (int i = 0; i < 4; ++i) {
                float v = acc[ct][i] + bias;
                hd[(lq * 4 + i) * HD_S + col] = f2bf(fmaxf(v, 0.f));
            }
        }
    }
    __syncthreads();

    // ---- out_u = hid @ W2 + b2, [16(8) x 128], K=256
    {
        const int cb = w * 16;
        f32x4 acc = (f32x4){0.f, 0.f, 0.f, 0.f};
        #pragma unroll
        for (int ks = 0; ks < HID / 32; ++ks) {
            bf16x8 a = *(const bf16x8*)&hd[l15 * HD_S + ks * 32 + lq * 8];
            bf16x8 b = *(const bf16x8*)&w2_t[(cb + l15) * HID + ks * 32 + lq * 8];
            acc = __builtin_amdgcn_mfma_f32_16x16x32_bf16(a, b, acc, 0, 0, 0);
        }
        const int col = cb + l15;
        const float bias = b2[col];
        #pragma unroll
        for (int i = 0; i < 4; ++i)
            ous[(lq * 4 + i) * NF + col] = acc[i] + bias;   // rows 0-15, 0-7 valid
    }
    __syncthreads();

    // ---- scatter: wave w broadcasts graph gbase+w (pure store stream)
    {
        const int lane = tid & 63;
        const int g = gbase + w;
        const int lo = offs[g];
        const int hi = offs[g + 1];

        const f32x4 v = *(const f32x4*)&ous[w * NF + (lane & 31) * 4];

        f32x4* out4 = (f32x4*)out;
        for (int i = lo * (NF / 4) + lane; i < hi * (NF / 4); i += 64)
            out4[i] = v;
    }
}

// ---------------------------------------------------------------------------
extern "C" void kernel_launch(void* const* d_in, const int* in_sizes, int n_in,
                              void* d_out, int out_size, void* d_ws, size_t ws_size,
                              hipStream_t stream) {
    const float* z    = (const float*)d_in[0];
    const int*   seg  = (const int*)  d_in[1];
    const float* wlp  = (const float*)d_in[2];
    const float* b_lp = (const float*)d_in[3];
    const float* w1   = (const float*)d_in[4];
    const float* b1   = (const float*)d_in[5];
    const float* w2   = (const float*)d_in[6];
    const float* b2   = (const float*)d_in[7];
    float* out = (float*)d_out;

    short* wlp_t = (short*)d_ws;                 // [512][256] bf16
    short* w1_t  = wlp_t + LATENT * H2;          // [256][512] bf16
    short* w2_t  = w1_t + H2 * HID;              // [128][256] bf16
    int*   offs  = (int*)(w2_t + HID * NF);      // [4097]

    prep_kernel<<<PREP_BLOCKS + SCAN_BLOCKS, 256, 0, stream>>>(
        wlp, w1, w2, seg, wlp_t, w1_t, w2_t, offs);
    mlp_scatter_kernel<<<MBLOCKS, MTHREADS, 0, stream>>>(
        z, offs, wlp_t, w1_t, w2_t, b_lp, b1, b2, out);
}

// Round 11
// 51.634 us; speedup vs baseline: 1.1854x; 1.1854x over previous
//
#include <hip/hip_runtime.h>
#include <hip/hip_bf16.h>

typedef __attribute__((ext_vector_type(8))) short bf16x8;
typedef __attribute__((ext_vector_type(4))) float f32x4;

#define NGRAPH   4096
#define NNODES   262144
#define LATENT   256
#define H2       512
#define HID      256
#define NF       128

#define PREP_BLOCKS 1152       // weight transpose (294912 / 256)

#define GPB      32            // graphs per block (mlp)
#define ATHREADS 512           // 8 waves
#define ABLOCKS  (NGRAPH / GPB)            // 128
#define SCAN_BLOCKS 64         // appended to mlp dispatch
#define IPT      8             // ints per scan thread (64*512*8 = 262144)

#define STHREADS 512           // 8 waves; 1 wave = 1 graph
#define SBLOCKS  (NGRAPH / 8)              // 512

// padded LDS strides
#define ZS_S 264
#define HS_S 520
#define HD_S 264

static __device__ __forceinline__ short f2bf(float x) {
    union { float f; unsigned u; } c; c.f = x;
    unsigned r = c.u + 0x7fffu + ((c.u >> 16) & 1u);   // RTNE
    return (short)(r >> 16);
}

// ---------------------------------------------------------------------------
// prep: W (fp32, [K][N] row-major) -> W^T (bf16, [N][K] row-major) in d_ws
// ---------------------------------------------------------------------------
__global__ __launch_bounds__(256) void prep_kernel(
    const float* __restrict__ wlp, const float* __restrict__ w1,
    const float* __restrict__ w2,
    short* __restrict__ wlp_t, short* __restrict__ w1_t, short* __restrict__ w2_t)
{
    int i = blockIdx.x * 256 + threadIdx.x;
    if (i < LATENT * H2) {                       // wlp_t [512][256]
        int n = i >> 8, k = i & 255;
        wlp_t[i] = f2bf(wlp[k * H2 + n]);
    } else if (i < 2 * LATENT * H2) {            // w1_t [256][512]
        int j = i - LATENT * H2;
        int n = j >> 9, k = j & 511;
        w1_t[j] = f2bf(w1[k * HID + n]);
    } else if (i < 2 * LATENT * H2 + HID * NF) { // w2_t [128][256]
        int j = i - 2 * LATENT * H2;
        int n = j >> 8, k = j & 255;
        w2_t[j] = f2bf(w2[k * NF + n]);
    }
}

// ---------------------------------------------------------------------------
// kernel A: blocks 0..127: 32-graph MLP -> ou.  blocks 128..191: seg scan
// -> offs (offs[g] = first node with seg >= g; consumed only by scatter).
// ---------------------------------------------------------------------------
__global__ __launch_bounds__(ATHREADS) void mlp_scan_kernel(
    const float* __restrict__ z, const int* __restrict__ seg,
    const short* __restrict__ wlp_t, const short* __restrict__ w1_t,
    const short* __restrict__ w2_t,
    const float* __restrict__ b_lp, const float* __restrict__ b1,
    const float* __restrict__ b2,
    float* __restrict__ ou, int* __restrict__ offs)
{
    __shared__ short zs[GPB * ZS_S];
    __shared__ short hs[GPB * HS_S];
    __shared__ short hd[GPB * HD_S];
    __shared__ float ous[GPB * NF];

    const int tid = threadIdx.x;

    if (blockIdx.x >= ABLOCKS) {
        // ---------------- scan role ----------------
        const int st = (blockIdx.x - ABLOCKS) * ATHREADS + tid;   // 0..32767
        const int base = st * IPT;
        int prev = (base == 0) ? -1 : seg[base - 1];
        int cur[IPT];
        #pragma unroll
        for (int j = 0; j < IPT; ++j) cur[j] = seg[base + j];
        #pragma unroll
        for (int j = 0; j < IPT; ++j) {
            int i = base + j;
            int s = cur[j];
            if (s != prev) {
                for (int g = prev + 1; g <= s; ++g) offs[g] = i;
            }
            prev = s;
        }
        if (base + IPT == NNODES) {                  // tail: (seg[N-1], NGRAPH]
            for (int g = prev + 1; g <= NGRAPH; ++g) offs[g] = NNODES;
        }
        return;
    }

    // ---------------- MLP role ----------------
    const int w   = tid >> 6;          // wave 0..7
    const int l15 = tid & 15;
    const int lq  = (tid >> 4) & 3;
    const int gbase = blockIdx.x * GPB;

    // ---- stage z: 32x256 fp32 -> bf16 LDS (padded)
    {
        const float4* zsrc = (const float4*)(z + (size_t)gbase * LATENT);
        #pragma unroll
        for (int it = 0; it < (GPB * LATENT / 4) / ATHREADS; ++it) {
            int idx = tid + it * ATHREADS;
            int row = idx >> 6, c4 = idx & 63;
            float4 v = zsrc[idx];
            short4 s4;
            s4.x = f2bf(v.x); s4.y = f2bf(v.y); s4.z = f2bf(v.z); s4.w = f2bf(v.w);
            *(short4*)&zs[row * ZS_S + c4 * 4] = s4;
        }
    }
    __syncthreads();

    // ---- h = relu(z @ Wlp + b_lp), [32 x 512], K=256
    {
        const int cb = w * 64;
        f32x4 acc[2][4];
        #pragma unroll
        for (int rt = 0; rt < 2; ++rt)
            #pragma unroll
            for (int ct = 0; ct < 4; ++ct) acc[rt][ct] = (f32x4){0.f, 0.f, 0.f, 0.f};
        #pragma unroll
        for (int ks = 0; ks < LATENT / 32; ++ks) {
            bf16x8 a0 = *(const bf16x8*)&zs[l15 * ZS_S + ks * 32 + lq * 8];
            bf16x8 a1 = *(const bf16x8*)&zs[(16 + l15) * ZS_S + ks * 32 + lq * 8];
            #pragma unroll
            for (int ct = 0; ct < 4; ++ct) {
                bf16x8 b = *(const bf16x8*)&wlp_t[(cb + ct * 16 + l15) * LATENT + ks * 32 + lq * 8];
                acc[0][ct] = __builtin_amdgcn_mfma_f32_16x16x32_bf16(a0, b, acc[0][ct], 0, 0, 0);
                acc[1][ct] = __builtin_amdgcn_mfma_f32_16x16x32_bf16(a1, b, acc[1][ct], 0, 0, 0);
            }
        }
        #pragma unroll
        for (int ct = 0; ct < 4; ++ct) {
            const int col = cb + ct * 16 + l15;
            const float bias = b_lp[col];
            #pragma unroll
            for (int rt = 0; rt < 2; ++rt)
                #pragma unroll
                for (int i = 0; i < 4; ++i) {
                    float v = acc[rt][ct][i] + bias;
                    hs[(rt * 16 + lq * 4 + i) * HS_S + col] = f2bf(fmaxf(v, 0.f));
                }
        }
    }
    __syncthreads();

    // ---- hid = relu(h @ W1 + b1), [32 x 256], K=512
    {
        const int cb = w * 32;
        f32x4 acc[2][2];
        #pragma unroll
        for (int rt = 0; rt < 2; ++rt)
            #pragma unroll
            for (int ct = 0; ct < 2; ++ct) acc[rt][ct] = (f32x4){0.f, 0.f, 0.f, 0.f};
        #pragma unroll
        for (int ks = 0; ks < H2 / 32; ++ks) {
            bf16x8 a0 = *(const bf16x8*)&hs[l15 * HS_S + ks * 32 + lq * 8];
            bf16x8 a1 = *(const bf16x8*)&hs[(16 + l15) * HS_S + ks * 32 + lq * 8];
            #pragma unroll
            for (int ct = 0; ct < 2; ++ct) {
                bf16x8 b = *(const bf16x8*)&w1_t[(cb + ct * 16 + l15) * H2 + ks * 32 + lq * 8];
                acc[0][ct] = __builtin_amdgcn_mfma_f32_16x16x32_bf16(a0, b, acc[0][ct], 0, 0, 0);
                acc[1][ct] = __builtin_amdgcn_mfma_f32_16x16x32_bf16(a1, b, acc[1][ct], 0, 0, 0);
            }
        }
        #pragma unroll
        for (int ct = 0; ct < 2; ++ct) {
            const int col = cb + ct * 16 + l15;
            const float bias = b1[col];
            #pragma unroll
            for (int rt = 0; rt < 2; ++rt)
                #pragma unroll
                for (int i = 0; i < 4; ++i) {
                    float v = acc[rt][ct][i] + bias;
                    hd[(rt * 16 + lq * 4 + i) * HD_S + col] = f2bf(fmaxf(v, 0.f));
                }
        }
    }
    __syncthreads();

    // ---- out_u = hid @ W2 + b2, [32 x 128], K=256
    {
        const int cb = w * 16;
        f32x4 acc[2];
        acc[0] = (f32x4){0.f, 0.f, 0.f, 0.f};
        acc[1] = (f32x4){0.f, 0.f, 0.f, 0.f};
        #pragma unroll
        for (int ks = 0; ks < HID / 32; ++ks) {
            bf16x8 a0 = *(const bf16x8*)&hd[l15 * HD_S + ks * 32 + lq * 8];
            bf16x8 a1 = *(const bf16x8*)&hd[(16 + l15) * HD_S + ks * 32 + lq * 8];
            bf16x8 b = *(const bf16x8*)&w2_t[(cb + l15) * HID + ks * 32 + lq * 8];
            acc[0] = __builtin_amdgcn_mfma_f32_16x16x32_bf16(a0, b, acc[0], 0, 0, 0);
            acc[1] = __builtin_amdgcn_mfma_f32_16x16x32_bf16(a1, b, acc[1], 0, 0, 0);
        }
        const int col = cb + l15;
        const float bias = b2[col];
        #pragma unroll
        for (int rt = 0; rt < 2; ++rt)
            #pragma unroll
            for (int i = 0; i < 4; ++i)
                ous[(rt * 16 + lq * 4 + i) * NF + col] = acc[rt][i] + bias;
    }
    __syncthreads();

    // ---- coalesced write of the 32x128 fp32 tile to global ws
    {
        float4* dst = (float4*)(ou + (size_t)gbase * NF);
        const float4* src = (const float4*)ous;
        #pragma unroll
        for (int it = 0; it < (GPB * NF / 4) / ATHREADS; ++it)
            dst[tid + it * ATHREADS] = src[tid + it * ATHREADS];
    }
}

// ---------------------------------------------------------------------------
// kernel B: per-graph streaming broadcast.  1 wave = 1 graph.
// offs lookup (2 loads) then pure store stream.
// ---------------------------------------------------------------------------
__global__ __launch_bounds__(STHREADS) void scatter_kernel(
    const int* __restrict__ offs, const float* __restrict__ ou,
    float* __restrict__ out)
{
    const int lane = threadIdx.x & 63;
    const int g = blockIdx.x * (STHREADS / 64) + (threadIdx.x >> 6);

    const int lo = offs[g];
    const int hi = offs[g + 1];

    const f32x4 v = ((const f32x4*)ou)[(size_t)g * (NF / 4) + (lane & 31)];

    f32x4* out4 = (f32x4*)out;
    for (int i = lo * (NF / 4) + lane; i < hi * (NF / 4); i += 64)
        out4[i] = v;
}

// ---------------------------------------------------------------------------
extern "C" void kernel_launch(void* const* d_in, const int* in_sizes, int n_in,
                              void* d_out, int out_size, void* d_ws, size_t ws_size,
                              hipStream_t stream) {
    const float* z    = (const float*)d_in[0];
    const int*   seg  = (const int*)  d_in[1];
    const float* wlp  = (const float*)d_in[2];
    const float* b_lp = (const float*)d_in[3];
    const float* w1   = (const float*)d_in[4];
    const float* b1   = (const float*)d_in[5];
    const float* w2   = (const float*)d_in[6];
    const float* b2   = (const float*)d_in[7];
    float* out = (float*)d_out;

    short* wlp_t = (short*)d_ws;                 // [512][256] bf16
    short* w1_t  = wlp_t + LATENT * H2;          // [256][512] bf16
    short* w2_t  = w1_t + H2 * HID;              // [128][256] bf16
    float* ou    = (float*)(w2_t + HID * NF);    // [4096][128] fp32 (16B aligned)
    int*   offs  = (int*)(ou + (size_t)NGRAPH * NF);   // [4097]

    prep_kernel<<<PREP_BLOCKS, 256, 0, stream>>>(wlp, w1, w2, wlp_t, w1_t, w2_t);
    mlp_scan_kernel<<<ABLOCKS + SCAN_BLOCKS, ATHREADS, 0, stream>>>(
        z, seg, wlp_t, w1_t, w2_t, b_lp, b1, b2, ou, offs);
    scatter_kernel<<<SBLOCKS, STHREADS, 0, stream>>>(offs, ou, out);
}

// Round 12
// 48.376 us; speedup vs baseline: 1.2653x; 1.0673x over previous
//
#include <hip/hip_runtime.h>
#include <hip/hip_bf16.h>

typedef __attribute__((ext_vector_type(8))) short bf16x8;
typedef __attribute__((ext_vector_type(4))) float f32x4;

#define NGRAPH   4096
#define NNODES   262144
#define LATENT   256
#define H2       512
#define HID      256
#define NF       128

#define PREP_BLOCKS 1152       // weight transpose (294912 / 256)
#define SCAN_BLOCKS 64         // seg -> offs scan
#define IPT         16         // ints per scan thread (64*256*16 = 262144)

#define GPB      16            // graphs per block (merged kernel)
#define MTHREADS 512           // 8 waves
#define MBLOCKS  (NGRAPH / GPB)            // 256 -> 1 block/CU

// padded LDS strides
#define ZS_S 264
#define HS_S 520
#define HD_S 264

static __device__ __forceinline__ short f2bf(float x) {
    union { float f; unsigned u; } c; c.f = x;
    unsigned r = c.u + 0x7fffu + ((c.u >> 16) & 1u);   // RTNE
    return (short)(r >> 16);
}

// ---------------------------------------------------------------------------
// dispatch 1: weight transpose -> bf16 (blocks 0..1151) + seg scan -> offs
// (blocks 1152..1215).  offs[g] = first node index with seg >= g.
// ---------------------------------------------------------------------------
__global__ __launch_bounds__(256) void prep_kernel(
    const float* __restrict__ wlp, const float* __restrict__ w1,
    const float* __restrict__ w2, const int* __restrict__ seg,
    short* __restrict__ wlp_t, short* __restrict__ w1_t, short* __restrict__ w2_t,
    int* __restrict__ offs)
{
    const int b = blockIdx.x;
    if (b < PREP_BLOCKS) {
        int i = b * 256 + threadIdx.x;
        if (i < LATENT * H2) {                       // wlp_t [512][256]
            int n = i >> 8, k = i & 255;
            wlp_t[i] = f2bf(wlp[k * H2 + n]);
        } else if (i < 2 * LATENT * H2) {            // w1_t [256][512]
            int j = i - LATENT * H2;
            int n = j >> 9, k = j & 511;
            w1_t[j] = f2bf(w1[k * HID + n]);
        } else if (i < 2 * LATENT * H2 + HID * NF) { // w2_t [128][256]
            int j = i - 2 * LATENT * H2;
            int n = j >> 8, k = j & 255;
            w2_t[j] = f2bf(w2[k * NF + n]);
        }
    } else {
        const int st = (b - PREP_BLOCKS) * 256 + threadIdx.x;   // 0..16383
        const int base = st * IPT;
        int prev = (base == 0) ? -1 : seg[base - 1];
        int cur[IPT];
        #pragma unroll
        for (int j = 0; j < IPT; ++j) cur[j] = seg[base + j];
        #pragma unroll
        for (int j = 0; j < IPT; ++j) {
            int i = base + j;
            int s = cur[j];
            if (s != prev) {
                for (int g = prev + 1; g <= s; ++g) offs[g] = i;
            }
            prev = s;
        }
        if (base + IPT == NNODES) {                  // tail: (seg[N-1], NGRAPH]
            for (int g = prev + 1; g <= NGRAPH; ++g) offs[g] = NNODES;
        }
    }
}

// ---------------------------------------------------------------------------
// dispatch 2: 16-graph MLP (MFMA, full tiles) + per-wave streaming broadcast
// of the block's own 16 graphs via LDS (no global ou round-trip).
// 256 blocks = 1/CU; store phase covers every CU.
// ---------------------------------------------------------------------------
__global__ __launch_bounds__(MTHREADS) void mlp_scatter_kernel(
    const float* __restrict__ z, const int* __restrict__ offs,
    const short* __restrict__ wlp_t, const short* __restrict__ w1_t,
    const short* __restrict__ w2_t,
    const float* __restrict__ b_lp, const float* __restrict__ b1,
    const float* __restrict__ b2,
    float* __restrict__ out)
{
    __shared__ short zs[GPB * ZS_S];
    __shared__ short hs[GPB * HS_S];
    __shared__ short hd[GPB * HD_S];
    __shared__ float ous[GPB * NF];

    const int tid = threadIdx.x;
    const int w   = tid >> 6;          // wave 0..7
    const int l15 = tid & 15;
    const int lq  = (tid >> 4) & 3;
    const int gbase = blockIdx.x * GPB;

    // ---- stage z: 16x256 fp32 -> bf16 LDS (padded)
    {
        const float4* zsrc = (const float4*)(z + (size_t)gbase * LATENT);
        #pragma unroll
        for (int it = 0; it < (GPB * LATENT / 4) / MTHREADS; ++it) {
            int idx = tid + it * MTHREADS;
            int row = idx >> 6, c4 = idx & 63;
            float4 v = zsrc[idx];
            short4 s4;
            s4.x = f2bf(v.x); s4.y = f2bf(v.y); s4.z = f2bf(v.z); s4.w = f2bf(v.w);
            *(short4*)&zs[row * ZS_S + c4 * 4] = s4;
        }
    }
    __syncthreads();

    // ---- h = relu(z @ Wlp + b_lp), [16 x 512], K=256
    {
        const int cb = w * 64;
        f32x4 acc[4];
        #pragma unroll
        for (int ct = 0; ct < 4; ++ct) acc[ct] = (f32x4){0.f, 0.f, 0.f, 0.f};
        #pragma unroll
        for (int ks = 0; ks < LATENT / 32; ++ks) {
            bf16x8 a = *(const bf16x8*)&zs[l15 * ZS_S + ks * 32 + lq * 8];
            #pragma unroll
            for (int ct = 0; ct < 4; ++ct) {
                bf16x8 b = *(const bf16x8*)&wlp_t[(cb + ct * 16 + l15) * LATENT + ks * 32 + lq * 8];
                acc[ct] = __builtin_amdgcn_mfma_f32_16x16x32_bf16(a, b, acc[ct], 0, 0, 0);
            }
        }
        #pragma unroll
        for (int ct = 0; ct < 4; ++ct) {
            const int col = cb + ct * 16 + l15;
            const float bias = b_lp[col];
            #pragma unroll
            for (int i = 0; i < 4; ++i) {
                float v = acc[ct][i] + bias;
                hs[(lq * 4 + i) * HS_S + col] = f2bf(fmaxf(v, 0.f));
            }
        }
    }
    __syncthreads();

    // ---- hid = relu(h @ W1 + b1), [16 x 256], K=512
    {
        const int cb = w * 32;
        f32x4 acc[2];
        #pragma unroll
        for (int ct = 0; ct < 2; ++ct) acc[ct] = (f32x4){0.f, 0.f, 0.f, 0.f};
        #pragma unroll
        for (int ks = 0; ks < H2 / 32; ++ks) {
            bf16x8 a = *(const bf16x8*)&hs[l15 * HS_S + ks * 32 + lq * 8];
            #pragma unroll
            for (int ct = 0; ct < 2; ++ct) {
                bf16x8 b = *(const bf16x8*)&w1_t[(cb + ct * 16 + l15) * H2 + ks * 32 + lq * 8];
                acc[ct] = __builtin_amdgcn_mfma_f32_16x16x32_bf16(a, b, acc[ct], 0, 0, 0);
            }
        }
        #pragma unroll
        for (int ct = 0; ct < 2; ++ct) {
            const int col = cb + ct * 16 + l15;
            const float bias = b1[col];
            #pragma unroll
            for (int i = 0; i < 4; ++i) {
                float v = acc[ct][i] + bias;
                hd[(lq * 4 + i) * HD_S + col] = f2bf(fmaxf(v, 0.f));
            }
        }
    }
    __syncthreads();

    // ---- out_u = hid @ W2 + b2, [16 x 128], K=256
    {
        const int cb = w * 16;
        f32x4 acc = (f32x4){0.f, 0.f, 0.f, 0.f};
        #pragma unroll
        for (int ks = 0; ks < HID / 32; ++ks) {
            bf16x8 a = *(const bf16x8*)&hd[l15 * HD_S + ks * 32 + lq * 8];
            bf16x8 b = *(const bf16x8*)&w2_t[(cb + l15) * HID + ks * 32 + lq * 8];
            acc = __builtin_amdgcn_mfma_f32_16x16x32_bf16(a, b, acc, 0, 0, 0);
        }
        const int col = cb + l15;
        const float bias = b2[col];
        #pragma unroll
        for (int i = 0; i < 4; ++i)
            ous[(lq * 4 + i) * NF + col] = acc[i] + bias;
    }
    __syncthreads();

    // ---- scatter: wave w broadcasts graphs gbase+2w, gbase+2w+1 (pure
    //      store streams; rows read once from LDS)
    {
        const int lane = tid & 63;
        f32x4* out4 = (f32x4*)out;
        #pragma unroll
        for (int q = 0; q < 2; ++q) {
            const int r = w * 2 + q;               // local row 0..15
            const int g = gbase + r;
            const int lo = offs[g];
            const int hi = offs[g + 1];
            const f32x4 v = *(const f32x4*)&ous[r * NF + (lane & 31) * 4];
            for (int i = lo * (NF / 4) + lane; i < hi * (NF / 4); i += 64)
                out4[i] = v;
        }
    }
}

// ---------------------------------------------------------------------------
extern "C" void kernel_launch(void* const* d_in, const int* in_sizes, int n_in,
                              void* d_out, int out_size, void* d_ws, size_t ws_size,
                              hipStream_t stream) {
    const float* z    = (const float*)d_in[0];
    const int*   seg  = (const int*)  d_in[1];
    const float* wlp  = (const float*)d_in[2];
    const float* b_lp = (const float*)d_in[3];
    const float* w1   = (const float*)d_in[4];
    const float* b1   = (const float*)d_in[5];
    const float* w2   = (const float*)d_in[6];
    const float* b2   = (const float*)d_in[7];
    float* out = (float*)d_out;

    short* wlp_t = (short*)d_ws;                 // [512][256] bf16
    short* w1_t  = wlp_t + LATENT * H2;          // [256][512] bf16
    short* w2_t  = w1_t + H2 * HID;              // [128][256] bf16
    int*   offs  = (int*)(w2_t + HID * NF);      // [4097]

    prep_kernel<<<PREP_BLOCKS + SCAN_BLOCKS, 256, 0, stream>>>(
        wlp, w1, w2, seg, wlp_t, w1_t, w2_t, offs);
    mlp_scatter_kernel<<<MBLOCKS, MTHREADS, 0, stream>>>(
        z, offs, wlp_t, w1_t, w2_t, b_lp, b1, b2, out);
}